// Round 1
// baseline (812.650 us; speedup 1.0000x reference)
//
#include <hip/hip_runtime.h>

// ---- problem constants ----
#define H       128
#define MAXNB   10
#define M_TREE  32768
#define NBOND   262144
#define NATOM   131072
#define FATOM   35
#define FBOND   40
#define FOUT    163
#define KPAD    192
#define NMOLS   4096
#define APM     32
#define TB      64      // bonds per block in mp_step
#define TA      64      // atoms per block in readout

typedef __bf16 bf16x8 __attribute__((ext_vector_type(8)));
typedef float  f32x4  __attribute__((ext_vector_type(4)));
typedef unsigned int u32x4 __attribute__((ext_vector_type(4)));
typedef unsigned int u32x2 __attribute__((ext_vector_type(2)));
typedef int          i32x4 __attribute__((ext_vector_type(4)));

__device__ __forceinline__ unsigned short f32_to_bf16(float f) {
  unsigned int u = __float_as_uint(f);
  u += 0x7FFFu + ((u >> 16) & 1u);   // RNE (no NaN in this data)
  return (unsigned short)(u >> 16);
}
__device__ __forceinline__ float bf16u_to_f32(unsigned short h) {
  return __uint_as_float(((unsigned int)h) << 16);
}
// packed pair: relu(bf16(a) + bf16(h)) -> packed bf16
__device__ __forceinline__ unsigned int bfpair_addrelu(unsigned int a, unsigned int h) {
  float a0 = __uint_as_float(a << 16), a1 = __uint_as_float(a & 0xFFFF0000u);
  float h0v = __uint_as_float(h << 16), h1v = __uint_as_float(h & 0xFFFF0000u);
  float r0 = fmaxf(a0 + h0v, 0.f), r1 = fmaxf(a1 + h1v, 0.f);
  return ((unsigned int)f32_to_bf16(r1) << 16) | (unsigned int)f32_to_bf16(r0);
}

// ---- prep: bf16 conversions + padded weight layouts + bond_graph remap + zero rows ----
// blocks [0,4096): tmsg vectorized. [4096,4288): weights. [4288,6848): bond_graph remap.
// block 6848: zero pad rows (index NBOND) of the two message buffers.
__global__ __launch_bounds__(256) void prep(const float* __restrict__ tm,
                                            const float* __restrict__ wh,
                                            const float* __restrict__ wo,
                                            const float* __restrict__ wi,
                                            const int* __restrict__ bond_graph,
                                            unsigned short* __restrict__ tmsg,
                                            unsigned short* __restrict__ whb,
                                            unsigned short* __restrict__ wob,
                                            unsigned short* __restrict__ wib,
                                            int* __restrict__ bg2,
                                            unsigned short* __restrict__ bufA,
                                            unsigned short* __restrict__ gm0) {
  const int blk = blockIdx.x;
  if (blk < 4096) {
    int i = (blk * 256 + threadIdx.x) * 4;      // < 4,194,304
    f32x4 v = __builtin_nontemporal_load((const f32x4*)(tm + i));
    u32x2 p;
    p.x = (unsigned int)f32_to_bf16(v.x) | ((unsigned int)f32_to_bf16(v.y) << 16);
    p.y = (unsigned int)f32_to_bf16(v.z) | ((unsigned int)f32_to_bf16(v.w) << 16);
    *(u32x2*)(tmsg + i) = p;
    return;
  }
  if (blk < 4288) {
    int j = (blk - 4096) * 256 + threadIdx.x;
    const int n2 = H * H;                 // 16,384
    const int n3 = H * KPAD;              // 24,576
    const int n4 = H * 64;                //  8,192
    if (j < n2) { whb[j] = f32_to_bf16(wh[j]); return; }
    int k = j - n2;
    if (k < n3) {
      int g = k / KPAD, kk = k - g * KPAD;
      float v = 0.f;
      if (kk < 35)                   v = wo[g * FOUT + kk];
      else if (kk >= 36 && kk < 164) v = wo[g * FOUT + kk - 1];
      wob[k] = f32_to_bf16(v);
      return;
    }
    int m = k - n3;
    if (m < n4) {
      int g = m / 64, kk = m - g * 64;
      wib[m] = (kk < FBOND) ? f32_to_bf16(wi[g * FBOND + kk]) : (unsigned short)0;
    }
    return;
  }
  if (blk < 4288 + 2560) {
    // remap: tree index -> zero row (NBOND); dynamic index -> idx - M_TREE
    int q = ((blk - 4288) * 256 + threadIdx.x) * 4;   // < 2,621,440 ints, exact
    i32x4 v = __builtin_nontemporal_load((const i32x4*)(bond_graph + q));
    i32x4 o;
    o.x = (v.x < M_TREE) ? NBOND : (v.x - M_TREE);
    o.y = (v.y < M_TREE) ? NBOND : (v.y - M_TREE);
    o.z = (v.z < M_TREE) ? NBOND : (v.z - M_TREE);
    o.w = (v.w < M_TREE) ? NBOND : (v.w - M_TREE);
    __builtin_nontemporal_store(o, (i32x4*)(bg2 + q));
    return;
  }
  // zero row NBOND of bufA (h0/gm1) and gm0 — mp_step never writes it, so it persists
  if (threadIdx.x < 128) {
    bufA[(size_t)NBOND * H + threadIdx.x] = 0;
    gm0 [(size_t)NBOND * H + threadIdx.x] = 0;
  }
}

// ---- fused: h0 = relu(F@Wi^T); hT = relu(F@Wi^T) + (sum_tree tmsg)@Wh^T ----
// Tree-neighbor contributions are static across all 5 MP rounds -> fold them into the
// bias once here. LDS: sT doubles as feats-staging (cols 0..63) then tree-sum tile.
__global__ __launch_bounds__(256, 3) void wi_gemm(const float* __restrict__ bond_feats,
                                                  const unsigned short* __restrict__ wib,
                                                  const unsigned short* __restrict__ whb,
                                                  const unsigned short* __restrict__ tmsg,
                                                  const int* __restrict__ bond_graph,
                                                  unsigned short* __restrict__ h0,
                                                  unsigned short* __restrict__ hT) {
  __shared__ unsigned short sT[128][136];     // 34,816 B
  __shared__ int sBG[128 * MAXNB];            //  5,120 B
  const int t = threadIdx.x;
  const int lane = t & 63;
  const int wave = t >> 6;
  const int n16 = lane & 15;
  const int quad = lane >> 4;
  const int b0 = blockIdx.x * 128;

  // flat float4 staging: 128 rows x 40 f32 = 1280 float4 (40 % 4 == 0: no row straddle)
#pragma unroll
  for (int c = 0; c < 5; ++c) {
    int q = c * 256 + t;
    f32x4 v = __builtin_nontemporal_load((const f32x4*)(bond_feats + (size_t)b0 * FBOND + q * 4));
    int flat = q * 4;
    int row = flat / 40, col = flat - row * 40;
    u32x2 p;
    p.x = (unsigned int)f32_to_bf16(v.x) | ((unsigned int)f32_to_bf16(v.y) << 16);
    p.y = (unsigned int)f32_to_bf16(v.z) | ((unsigned int)f32_to_bf16(v.w) << 16);
    *(u32x2*)&sT[row][col] = p;
  }
  for (int i = t; i < 128 * 24; i += 256) {    // zero cols 40..63
    int b = i / 24, c = 40 + i - b * 24;
    sT[b][c] = 0;
  }
  for (int i = t; i < 128 * MAXNB; i += 256)
    sBG[i] = __builtin_nontemporal_load(bond_graph + (size_t)b0 * MAXNB + i);

  bf16x8 Bi[2][2];
#pragma unroll
  for (int kt = 0; kt < 2; ++kt)
#pragma unroll
    for (int nt = 0; nt < 2; ++nt)
      Bi[kt][nt] = *(const bf16x8*)(wib + ((wave * 2 + nt) * 16 + n16) * 64 + kt * 32 + quad * 8);
  __syncthreads();

  f32x4 acc[8][2];
  f32x4 zero = {0.f, 0.f, 0.f, 0.f};
#pragma unroll
  for (int mt = 0; mt < 8; ++mt) { acc[mt][0] = zero; acc[mt][1] = zero; }
#pragma unroll
  for (int kt = 0; kt < 2; ++kt)
#pragma unroll
    for (int mt = 0; mt < 8; ++mt) {
      bf16x8 av = *(const bf16x8*)&sT[mt * 16 + n16][kt * 32 + quad * 8];
      acc[mt][0] = __builtin_amdgcn_mfma_f32_16x16x32_bf16(av, Bi[kt][0], acc[mt][0], 0, 0, 0);
      acc[mt][1] = __builtin_amdgcn_mfma_f32_16x16x32_bf16(av, Bi[kt][1], acc[mt][1], 0, 0, 0);
    }
  // write h0 (gather source for round 1) now; keep acc live for the hT epilogue
#pragma unroll
  for (int mt = 0; mt < 8; ++mt)
#pragma unroll
    for (int nt = 0; nt < 2; ++nt) {
      const int col = (wave * 2 + nt) * 16 + n16;
#pragma unroll
      for (int r = 0; r < 4; ++r) {
        const int b = b0 + mt * 16 + quad * 4 + r;
        __builtin_nontemporal_store(f32_to_bf16(fmaxf(acc[mt][nt][r], 0.f)), &h0[(size_t)b * H + col]);
      }
    }
  __syncthreads();   // all MFMA#1 reads of sT done -> safe to overwrite with tree sums

  // gather static tree-neighbor sums (uniform scalar branch per index; ~1/9 hit rate)
  for (int lb = wave * 4; lb < 128; lb += 16) {
#pragma unroll
    for (int p = 0; p < 4; ++p) {
      const int* ig = &sBG[(lb + p) * MAXNB];
      float a0 = 0.f, a1 = 0.f;
#pragma unroll
      for (int j = 0; j < MAXNB; ++j) {
        int idx = __builtin_amdgcn_readfirstlane(ig[j]);
        if (idx < M_TREE) {
          unsigned int u = *(const unsigned int*)(tmsg + (size_t)idx * H + 2 * lane);
          a0 += __uint_as_float(u << 16);
          a1 += __uint_as_float(u & 0xFFFF0000u);
        }
      }
      unsigned int packed = ((unsigned int)f32_to_bf16(a1) << 16) | (unsigned int)f32_to_bf16(a0);
      *(unsigned int*)&sT[lb + p][2 * lane] = packed;
    }
  }

  bf16x8 Bh[4][2];
#pragma unroll
  for (int kt = 0; kt < 4; ++kt)
#pragma unroll
    for (int nt = 0; nt < 2; ++nt)
      Bh[kt][nt] = *(const bf16x8*)(whb + ((wave * 2 + nt) * 16 + n16) * H + kt * 32 + quad * 8);
  __syncthreads();

  // MFMA#2 per output row-tile, immediate epilogue (caps live accumulators)
#pragma unroll
  for (int mt = 0; mt < 8; ++mt) {
    f32x4 acch[2] = {zero, zero};
#pragma unroll
    for (int kt = 0; kt < 4; ++kt) {
      bf16x8 av = *(const bf16x8*)&sT[mt * 16 + n16][kt * 32 + quad * 8];
      acch[0] = __builtin_amdgcn_mfma_f32_16x16x32_bf16(av, Bh[kt][0], acch[0], 0, 0, 0);
      acch[1] = __builtin_amdgcn_mfma_f32_16x16x32_bf16(av, Bh[kt][1], acch[1], 0, 0, 0);
    }
#pragma unroll
    for (int nt = 0; nt < 2; ++nt) {
      const int col = (wave * 2 + nt) * 16 + n16;
#pragma unroll
      for (int r = 0; r < 4; ++r) {
        const int b = b0 + mt * 16 + quad * 4 + r;
        float hr = fmaxf(acc[mt][nt][r], 0.f);
        __builtin_nontemporal_store(f32_to_bf16(hr + acch[nt][r]), &hT[(size_t)b * H + col]);
      }
    }
  }
}

// ---- one MP round: gm_out = relu(hT + gather_dyn(gm_in)@W_h^T) ----
// bg2 is pre-remapped: tree slots point at the zero row (NBOND), dyn slots are direct
// row indices into gm_in. No branch, no tmsg; streaming traffic is all non-temporal
// so L2 stays reserved for the 67 MB gather pool.
__global__ __launch_bounds__(256, 6) void mp_step(const unsigned short* __restrict__ gm_in,
                                                  unsigned short* __restrict__ gm_out,
                                                  const unsigned short* __restrict__ hT,
                                                  const int* __restrict__ bg2,
                                                  const unsigned short* __restrict__ whb) {
  __shared__ unsigned short snei[TB][136];   // 17408 B
  __shared__ int sBG[TB * MAXNB];            //  2560 B
  const int t = threadIdx.x;
  const int lane = t & 63;
  const int wave = t >> 6;
  const int n16 = lane & 15;
  const int quad = lane >> 4;
  const int b0 = blockIdx.x * TB;

  for (int i = t; i < TB * MAXNB; i += 256)
    sBG[i] = __builtin_nontemporal_load(bg2 + (size_t)b0 * MAXNB + i);
  __syncthreads();

  // gather: wave-uniform indices -> SALU addressing; 4 bonds/iter = 40 loads in flight
  for (int lb = wave * 4; lb < TB; lb += 16) {
    unsigned int u[4][MAXNB];
#pragma unroll
    for (int p = 0; p < 4; ++p) {
      const int* ig = &sBG[(lb + p) * MAXNB];
#pragma unroll
      for (int j = 0; j < MAXNB; ++j) {
        int idx = __builtin_amdgcn_readfirstlane(ig[j]);
        u[p][j] = *(const unsigned int*)(gm_in + (size_t)idx * H + 2 * lane);
      }
    }
#pragma unroll
    for (int p = 0; p < 4; ++p) {
      float a0 = 0.f, a1 = 0.f;
#pragma unroll
      for (int j = 0; j < MAXNB; ++j) {
        a0 += __uint_as_float(u[p][j] << 16);
        a1 += __uint_as_float(u[p][j] & 0xFFFF0000u);
      }
      unsigned int packed = ((unsigned int)f32_to_bf16(a1) << 16) | (unsigned int)f32_to_bf16(a0);
      *(unsigned int*)&snei[lb + p][2 * lane] = packed;
    }
  }

  // W_h^T fragments (after gather to limit register overlap): 32 VGPRs
  bf16x8 Bf[4][2];
#pragma unroll
  for (int kt = 0; kt < 4; ++kt)
#pragma unroll
    for (int nt = 0; nt < 2; ++nt)
      Bf[kt][nt] = *(const bf16x8*)(whb + ((wave * 2 + nt) * 16 + n16) * H + kt * 32 + quad * 8);
  __syncthreads();

  f32x4 acc[4][2];
  f32x4 zero = {0.f, 0.f, 0.f, 0.f};
#pragma unroll
  for (int mt = 0; mt < 4; ++mt) { acc[mt][0] = zero; acc[mt][1] = zero; }
#pragma unroll
  for (int kt = 0; kt < 4; ++kt)
#pragma unroll
    for (int mt = 0; mt < 4; ++mt) {
      bf16x8 av = *(const bf16x8*)&snei[mt * 16 + n16][kt * 32 + quad * 8];
      acc[mt][0] = __builtin_amdgcn_mfma_f32_16x16x32_bf16(av, Bf[kt][0], acc[mt][0], 0, 0, 0);
      acc[mt][1] = __builtin_amdgcn_mfma_f32_16x16x32_bf16(av, Bf[kt][1], acc[mt][1], 0, 0, 0);
    }
  __syncthreads();   // all MFMA reads of snei done

  // stage acc -> snei as bf16
#pragma unroll
  for (int mt = 0; mt < 4; ++mt)
#pragma unroll
    for (int nt = 0; nt < 2; ++nt) {
      const int col = (wave * 2 + nt) * 16 + n16;
#pragma unroll
      for (int r = 0; r < 4; ++r)
        snei[mt * 16 + quad * 4 + r][col] = f32_to_bf16(acc[mt][nt][r]);
    }
  __syncthreads();

  // vectorized epilogue: 64 rows x 16 chunks = 1024 -> 4/thread
  const size_t gbase = (size_t)b0 * H;
#pragma unroll
  for (int c = 0; c < 4; ++c) {
    int fl = c * 256 + t;
    int row = fl >> 4;
    int col = (fl & 15) * 8;
    u32x4 a4 = *(const u32x4*)&snei[row][col];
    u32x4 h4 = __builtin_nontemporal_load((const u32x4*)(hT + gbase + (size_t)row * H + col));
    u32x4 o4;
    o4.x = bfpair_addrelu(a4.x, h4.x);
    o4.y = bfpair_addrelu(a4.y, h4.y);
    o4.z = bfpair_addrelu(a4.z, h4.z);
    o4.w = bfpair_addrelu(a4.w, h4.w);
    __builtin_nontemporal_store(o4, (u32x4*)(gm_out + gbase + (size_t)row * H + col));
  }
}

// ---- readout: 64 atoms (2 mols)/block, MFMA over K=192, 5 blocks/CU ----
__global__ __launch_bounds__(256, 5) void readout(const float* __restrict__ atom_feats,
                                                  const unsigned short* __restrict__ gm,
                                                  const unsigned short* __restrict__ tmsg,
                                                  const int* __restrict__ atom_graph,
                                                  const unsigned short* __restrict__ wob,
                                                  const float* __restrict__ b_o,
                                                  float* __restrict__ out) {
  __shared__ unsigned short sA[TA][200];     // 25600 B
  __shared__ int sAG[TA * MAXNB];            //  2560 B
  const int t = threadIdx.x;
  const int lane = t & 63;
  const int wave = t >> 6;
  const int n16 = lane & 15;
  const int quad = lane >> 4;
  const int blk = blockIdx.x;
  const int abase = blk * TA;

  for (int i = t; i < TA * MAXNB; i += 256)
    sAG[i] = __builtin_nontemporal_load(atom_graph + abase * MAXNB + i);
  for (int i = t; i < TA * FATOM; i += 256) {
    int a = i / FATOM, f = i - a * FATOM;
    sA[a][f] = f32_to_bf16(__builtin_nontemporal_load(atom_feats + abase * FATOM + i));
  }
  if (t < TA) sA[t][35] = 0;
  for (int i = t; i < TA * 28; i += 256) {
    int a = i / 28, c = 164 + i - a * 28;
    sA[a][c] = 0;
  }
  __syncthreads();

  const unsigned short* gsh = gm - (size_t)M_TREE * H;
  for (int la = wave * 2; la < TA; la += 8) {
    unsigned int u[2][MAXNB];
#pragma unroll
    for (int p = 0; p < 2; ++p) {
      const int* ig = &sAG[(la + p) * MAXNB];
#pragma unroll
      for (int j = 0; j < MAXNB; ++j) {
        int idx = __builtin_amdgcn_readfirstlane(ig[j]);
        const unsigned short* r = ((idx < M_TREE) ? tmsg : gsh) + (size_t)idx * H;
        u[p][j] = *(const unsigned int*)(r + 2 * lane);
      }
    }
#pragma unroll
    for (int p = 0; p < 2; ++p) {
      float a0 = 0.f, a1 = 0.f;
#pragma unroll
      for (int j = 0; j < MAXNB; ++j) {
        a0 += __uint_as_float(u[p][j] << 16);
        a1 += __uint_as_float(u[p][j] & 0xFFFF0000u);
      }
      unsigned int packed = ((unsigned int)f32_to_bf16(a1) << 16) | (unsigned int)f32_to_bf16(a0);
      *(unsigned int*)&sA[la + p][36 + 2 * lane] = packed;
    }
  }

  bf16x8 Bf[6][2];
#pragma unroll
  for (int kt = 0; kt < 6; ++kt)
#pragma unroll
    for (int nt = 0; nt < 2; ++nt)
      Bf[kt][nt] = *(const bf16x8*)(wob + ((wave * 2 + nt) * 16 + n16) * KPAD + kt * 32 + quad * 8);
  __syncthreads();

  f32x4 acc[4][2];
  f32x4 zero = {0.f, 0.f, 0.f, 0.f};
#pragma unroll
  for (int mt = 0; mt < 4; ++mt) { acc[mt][0] = zero; acc[mt][1] = zero; }
#pragma unroll
  for (int kt = 0; kt < 6; ++kt)
#pragma unroll
    for (int mt = 0; mt < 4; ++mt) {
      bf16x8 av = *(const bf16x8*)&sA[mt * 16 + n16][kt * 32 + quad * 8];
      acc[mt][0] = __builtin_amdgcn_mfma_f32_16x16x32_bf16(av, Bf[kt][0], acc[mt][0], 0, 0, 0);
      acc[mt][1] = __builtin_amdgcn_mfma_f32_16x16x32_bf16(av, Bf[kt][1], acc[mt][1], 0, 0, 0);
    }

  float bo[2] = { b_o[(wave * 2) * 16 + n16], b_o[(wave * 2 + 1) * 16 + n16] };
  float part[2][2] = {{0.f,0.f},{0.f,0.f}};
#pragma unroll
  for (int mt = 0; mt < 4; ++mt)
#pragma unroll
    for (int nt = 0; nt < 2; ++nt)
#pragma unroll
      for (int r = 0; r < 4; ++r)
        part[mt >> 1][nt] += fmaxf(acc[mt][nt][r] + bo[nt], 0.f);
#pragma unroll
  for (int mol = 0; mol < 2; ++mol)
#pragma unroll
    for (int nt = 0; nt < 2; ++nt) {
      float p = part[mol][nt];
      p += __shfl_xor(p, 16);
      p += __shfl_xor(p, 32);
      if (lane < 16)
        out[(blk * 2 + mol) * H + (wave * 2 + nt) * 16 + lane] = p * (1.0f / APM);
    }
}

extern "C" void kernel_launch(void* const* d_in, const int* in_sizes, int n_in,
                              void* d_out, int out_size, void* d_ws, size_t ws_size,
                              hipStream_t stream) {
  (void)in_sizes; (void)n_in; (void)out_size; (void)ws_size;
  const float* atom_feats   = (const float*)d_in[0];
  const float* bond_feats   = (const float*)d_in[1];
  const float* tree_message = (const float*)d_in[2];
  const int*   atom_graph   = (const int*)d_in[3];
  const int*   bond_graph   = (const int*)d_in[4];
  const float* W_i = (const float*)d_in[6];
  const float* W_h = (const float*)d_in[7];
  const float* W_o = (const float*)d_in[8];
  const float* b_o = (const float*)d_in[9];
  float* out = (float*)d_out;

  char* ws = (char*)d_ws;
  unsigned short* tmsg = (unsigned short*)(ws);                    //  8,388,608 B
  unsigned short* whb  = (unsigned short*)(ws + 8388608);          //     32,768 B
  unsigned short* wob  = (unsigned short*)(ws + 8421376);          //     49,152 B
  unsigned short* wib  = (unsigned short*)(ws + 8470528);          //     16,384 B
  int*            bg2  = (int*)           (ws + 8486912);          // 10,485,760 B
  unsigned short* bufA = (unsigned short*)(ws + 18972672);         // 67,109,120 B (h0, then gm1)
  unsigned short* gm0  = (unsigned short*)(ws + 86081792);         // 67,109,120 B
  unsigned short* hT   = (unsigned short*)(ws + 153190912);        // 67,108,864 B -> 220,299,776 total

  prep<<<6849, 256, 0, stream>>>(tree_message, W_h, W_o, W_i, bond_graph,
                                 tmsg, whb, wob, wib, bg2, bufA, gm0);
  wi_gemm<<<NBOND / 128, 256, 0, stream>>>(bond_feats, wib, whb, tmsg, bond_graph, bufA, hT);
  // bufA (h0) is dead as a gather source after round 1 -> reuse as gm1
  mp_step<<<NBOND / TB, 256, 0, stream>>>(bufA, gm0, hT, bg2, whb);
  mp_step<<<NBOND / TB, 256, 0, stream>>>(gm0, bufA, hT, bg2, whb);
  mp_step<<<NBOND / TB, 256, 0, stream>>>(bufA, gm0, hT, bg2, whb);
  mp_step<<<NBOND / TB, 256, 0, stream>>>(gm0, bufA, hT, bg2, whb);
  mp_step<<<NBOND / TB, 256, 0, stream>>>(bufA, gm0, hT, bg2, whb);
  readout<<<NATOM / TA, 256, 0, stream>>>(atom_feats, gm0, tmsg, atom_graph, wob, b_o, out);
}

// Round 2
// 775.443 us; speedup vs baseline: 1.0480x; 1.0480x over previous
//
#include <hip/hip_runtime.h>

// ---- problem constants ----
#define H       128
#define MAXNB   10
#define M_TREE  32768
#define NBOND   262144
#define NATOM   131072
#define FATOM   35
#define FBOND   40
#define FOUT    163
#define KPAD    192
#define NMOLS   4096
#define APM     32
#define TB      64      // bonds per block in mp_step
#define TA      64      // atoms per block in readout

typedef __bf16 bf16x8 __attribute__((ext_vector_type(8)));
typedef float  f32x4  __attribute__((ext_vector_type(4)));
typedef unsigned int u32x4 __attribute__((ext_vector_type(4)));
typedef unsigned int u32x2 __attribute__((ext_vector_type(2)));

__device__ __forceinline__ unsigned short f32_to_bf16(float f) {
  unsigned int u = __float_as_uint(f);
  u += 0x7FFFu + ((u >> 16) & 1u);   // RNE (no NaN in this data)
  return (unsigned short)(u >> 16);
}
__device__ __forceinline__ float bf16u_to_f32(unsigned short h) {
  return __uint_as_float(((unsigned int)h) << 16);
}
// packed pair: relu(bf16(a) + bf16(h)) -> packed bf16
__device__ __forceinline__ unsigned int bfpair_addrelu(unsigned int a, unsigned int h) {
  float a0 = __uint_as_float(a << 16), a1 = __uint_as_float(a & 0xFFFF0000u);
  float h0v = __uint_as_float(h << 16), h1v = __uint_as_float(h & 0xFFFF0000u);
  float r0 = fmaxf(a0 + h0v, 0.f), r1 = fmaxf(a1 + h1v, 0.f);
  return ((unsigned int)f32_to_bf16(r1) << 16) | (unsigned int)f32_to_bf16(r0);
}
// a0 += lo(u), a1 += hi(u): 2 VALU ops instead of 4 (exact: bf16*1.0, f32 acc)
__device__ __forceinline__ void bfdot_acc(unsigned int u, float& a0, float& a1) {
  asm("v_dot2_f32_bf16 %0, %1, %2, %0" : "+v"(a0) : "v"(u), "v"(0x00003F80u));
  asm("v_dot2_f32_bf16 %0, %1, %2, %0" : "+v"(a1) : "v"(u), "v"(0x3F800000u));
}

// ---- prep: bf16 conversions + padded weight layouts ----
// blocks [0,4096): tmsg vectorized (4 f32/thread). blocks [4096,4288): weights scalar.
__global__ __launch_bounds__(256) void prep(const float* __restrict__ tm,
                                            const float* __restrict__ wh,
                                            const float* __restrict__ wo,
                                            const float* __restrict__ wi,
                                            unsigned short* __restrict__ tmsg,
                                            unsigned short* __restrict__ whb,
                                            unsigned short* __restrict__ wob,
                                            unsigned short* __restrict__ wib) {
  const int blk = blockIdx.x;
  if (blk < 4096) {
    int i = (blk * 256 + threadIdx.x) * 4;      // < 4,194,304
    f32x4 v = __builtin_nontemporal_load((const f32x4*)(tm + i));
    u32x2 p;
    p.x = (unsigned int)f32_to_bf16(v.x) | ((unsigned int)f32_to_bf16(v.y) << 16);
    p.y = (unsigned int)f32_to_bf16(v.z) | ((unsigned int)f32_to_bf16(v.w) << 16);
    *(u32x2*)(tmsg + i) = p;
    return;
  }
  int j = (blk - 4096) * 256 + threadIdx.x;
  const int n2 = H * H;                 // 16,384
  const int n3 = H * KPAD;              // 24,576
  const int n4 = H * 64;                //  8,192
  if (j < n2) { whb[j] = f32_to_bf16(wh[j]); return; }
  int k = j - n2;
  if (k < n3) {
    int g = k / KPAD, kk = k - g * KPAD;
    float v = 0.f;
    if (kk < 35)                   v = wo[g * FOUT + kk];
    else if (kk >= 36 && kk < 164) v = wo[g * FOUT + kk - 1];
    wob[k] = f32_to_bf16(v);
    return;
  }
  int m = k - n3;
  if (m < n4) {
    int g = m / 64, kk = m - g * 64;
    wib[m] = (kk < FBOND) ? f32_to_bf16(wi[g * FBOND + kk]) : (unsigned short)0;
  }
}

// ---- h0 = relu(bond_feats @ W_i^T), MFMA, stored bf16 ----
__global__ __launch_bounds__(256, 3) void wi_gemm(const float* __restrict__ bond_feats,
                                                  const unsigned short* __restrict__ wib,
                                                  unsigned short* __restrict__ h0) {
  __shared__ unsigned short sF[128][72];
  const int t = threadIdx.x;
  const int lane = t & 63;
  const int wave = t >> 6;
  const int n16 = lane & 15;
  const int quad = lane >> 4;
  const int b0 = blockIdx.x * 128;

  // flat float4 staging: 128 rows x 40 f32 = 1280 float4 (40 % 4 == 0: no row straddle)
#pragma unroll
  for (int c = 0; c < 5; ++c) {
    int q = c * 256 + t;
    f32x4 v = __builtin_nontemporal_load((const f32x4*)(bond_feats + (size_t)b0 * FBOND + q * 4));
    int flat = q * 4;
    int row = flat / 40, col = flat - row * 40;
    u32x2 p;
    p.x = (unsigned int)f32_to_bf16(v.x) | ((unsigned int)f32_to_bf16(v.y) << 16);
    p.y = (unsigned int)f32_to_bf16(v.z) | ((unsigned int)f32_to_bf16(v.w) << 16);
    *(u32x2*)&sF[row][col] = p;
  }
  for (int i = t; i < 128 * 24; i += 256) {    // zero cols 40..63
    int b = i / 24, c = 40 + i - b * 24;
    sF[b][c] = 0;
  }
  bf16x8 Bf[2][2];
#pragma unroll
  for (int kt = 0; kt < 2; ++kt)
#pragma unroll
    for (int nt = 0; nt < 2; ++nt)
      Bf[kt][nt] = *(const bf16x8*)(wib + ((wave * 2 + nt) * 16 + n16) * 64 + kt * 32 + quad * 8);
  __syncthreads();

  f32x4 acc[8][2];
  f32x4 zero = {0.f, 0.f, 0.f, 0.f};
#pragma unroll
  for (int mt = 0; mt < 8; ++mt) { acc[mt][0] = zero; acc[mt][1] = zero; }
#pragma unroll
  for (int kt = 0; kt < 2; ++kt)
#pragma unroll
    for (int mt = 0; mt < 8; ++mt) {
      bf16x8 av = *(const bf16x8*)&sF[mt * 16 + n16][kt * 32 + quad * 8];
      acc[mt][0] = __builtin_amdgcn_mfma_f32_16x16x32_bf16(av, Bf[kt][0], acc[mt][0], 0, 0, 0);
      acc[mt][1] = __builtin_amdgcn_mfma_f32_16x16x32_bf16(av, Bf[kt][1], acc[mt][1], 0, 0, 0);
    }
#pragma unroll
  for (int mt = 0; mt < 8; ++mt)
#pragma unroll
    for (int nt = 0; nt < 2; ++nt) {
      const int col = (wave * 2 + nt) * 16 + n16;
#pragma unroll
      for (int r = 0; r < 4; ++r) {
        const int b = b0 + mt * 16 + quad * 4 + r;
        h0[b * H + col] = f32_to_bf16(fmaxf(acc[mt][nt][r], 0.f));
      }
    }
}

// ---- one MP round: gm_out = relu(h0 + gather(msg)@W_h^T) ----
// (256,4): 128-VGPR cap so the 80-dword gather batch (8 bonds x 10 nbrs) truly sits
// in flight; previous (256,6) build had VGPR_Count=36 -> compiler chopped MLP to ~10.
__global__ __launch_bounds__(256, 4) void mp_step(const unsigned short* __restrict__ gm_in,
                                                  unsigned short* __restrict__ gm_out,
                                                  const unsigned short* __restrict__ h0,
                                                  const unsigned short* __restrict__ tmsg,
                                                  const int* __restrict__ bond_graph,
                                                  const unsigned short* __restrict__ whb) {
  __shared__ unsigned short snei[TB][136];   // 17408 B
  __shared__ int sBG[TB * MAXNB];            //  2560 B
  const int t = threadIdx.x;
  const int lane = t & 63;
  const int wave = t >> 6;
  const int n16 = lane & 15;
  const int quad = lane >> 4;
  const int b0 = blockIdx.x * TB;

  for (int i = t; i < TB * MAXNB; i += 256) sBG[i] = bond_graph[b0 * MAXNB + i];
  __syncthreads();

  // prefetch epilogue bias rows (streams 67 MB/step; hide it under gather latency)
  const size_t gbase = (size_t)b0 * H;
  u32x4 h4[4];
#pragma unroll
  for (int c = 0; c < 4; ++c) {
    int fl = c * 256 + t;
    h4[c] = __builtin_nontemporal_load(
        (const u32x4*)(h0 + gbase + (size_t)(fl >> 4) * H + (fl & 15) * 8));
  }

  const unsigned short* gsh = gm_in - (size_t)M_TREE * H;
  // gather: wave-uniform indices -> SALU addressing; 8 bonds/iter = 80 loads in flight
  for (int lb = wave * 8; lb < TB; lb += 32) {
    unsigned int u[8][MAXNB];
#pragma unroll
    for (int p = 0; p < 8; ++p) {
      const int* ig = &sBG[(lb + p) * MAXNB];
#pragma unroll
      for (int j = 0; j < MAXNB; ++j) {
        int idx = __builtin_amdgcn_readfirstlane(ig[j]);
        const unsigned short* r = ((idx < M_TREE) ? tmsg : gsh) + (size_t)idx * H;
        u[p][j] = *(const unsigned int*)(r + 2 * lane);
      }
    }
#pragma unroll
    for (int p = 0; p < 8; ++p) {
      float a0 = 0.f, a1 = 0.f;
#pragma unroll
      for (int j = 0; j < MAXNB; ++j) bfdot_acc(u[p][j], a0, a1);
      unsigned int packed = ((unsigned int)f32_to_bf16(a1) << 16) | (unsigned int)f32_to_bf16(a0);
      *(unsigned int*)&snei[lb + p][2 * lane] = packed;
    }
  }

  // W_h^T fragments (after gather to limit register overlap): 32 VGPRs
  bf16x8 Bf[4][2];
#pragma unroll
  for (int kt = 0; kt < 4; ++kt)
#pragma unroll
    for (int nt = 0; nt < 2; ++nt)
      Bf[kt][nt] = *(const bf16x8*)(whb + ((wave * 2 + nt) * 16 + n16) * H + kt * 32 + quad * 8);
  __syncthreads();

  f32x4 acc[4][2];
  f32x4 zero = {0.f, 0.f, 0.f, 0.f};
#pragma unroll
  for (int mt = 0; mt < 4; ++mt) { acc[mt][0] = zero; acc[mt][1] = zero; }
#pragma unroll
  for (int kt = 0; kt < 4; ++kt)
#pragma unroll
    for (int mt = 0; mt < 4; ++mt) {
      bf16x8 av = *(const bf16x8*)&snei[mt * 16 + n16][kt * 32 + quad * 8];
      acc[mt][0] = __builtin_amdgcn_mfma_f32_16x16x32_bf16(av, Bf[kt][0], acc[mt][0], 0, 0, 0);
      acc[mt][1] = __builtin_amdgcn_mfma_f32_16x16x32_bf16(av, Bf[kt][1], acc[mt][1], 0, 0, 0);
    }
  __syncthreads();   // all MFMA reads of snei done

  // stage acc -> snei as bf16
#pragma unroll
  for (int mt = 0; mt < 4; ++mt)
#pragma unroll
    for (int nt = 0; nt < 2; ++nt) {
      const int col = (wave * 2 + nt) * 16 + n16;
#pragma unroll
      for (int r = 0; r < 4; ++r)
        snei[mt * 16 + quad * 4 + r][col] = f32_to_bf16(acc[mt][nt][r]);
    }
  __syncthreads();

  // vectorized epilogue: 64 rows x 16 chunks = 1024 -> 4/thread (bias already in h4)
#pragma unroll
  for (int c = 0; c < 4; ++c) {
    int fl = c * 256 + t;
    int row = fl >> 4;
    int col = (fl & 15) * 8;
    u32x4 a4 = *(const u32x4*)&snei[row][col];
    u32x4 o4;
    o4.x = bfpair_addrelu(a4.x, h4[c].x);
    o4.y = bfpair_addrelu(a4.y, h4[c].y);
    o4.z = bfpair_addrelu(a4.z, h4[c].z);
    o4.w = bfpair_addrelu(a4.w, h4[c].w);
    *(u32x4*)(gm_out + gbase + (size_t)row * H + col) = o4;
  }
}

// ---- readout: 64 atoms (2 mols)/block, MFMA over K=192, same MLP treatment ----
__global__ __launch_bounds__(256, 4) void readout(const float* __restrict__ atom_feats,
                                                  const unsigned short* __restrict__ gm,
                                                  const unsigned short* __restrict__ tmsg,
                                                  const int* __restrict__ atom_graph,
                                                  const unsigned short* __restrict__ wob,
                                                  const float* __restrict__ b_o,
                                                  float* __restrict__ out) {
  __shared__ unsigned short sA[TA][200];     // 25600 B
  __shared__ int sAG[TA * MAXNB];            //  2560 B
  const int t = threadIdx.x;
  const int lane = t & 63;
  const int wave = t >> 6;
  const int n16 = lane & 15;
  const int quad = lane >> 4;
  const int blk = blockIdx.x;
  const int abase = blk * TA;

  for (int i = t; i < TA * MAXNB; i += 256)
    sAG[i] = __builtin_nontemporal_load(atom_graph + abase * MAXNB + i);
  for (int i = t; i < TA * FATOM; i += 256) {
    int a = i / FATOM, f = i - a * FATOM;
    sA[a][f] = f32_to_bf16(__builtin_nontemporal_load(atom_feats + abase * FATOM + i));
  }
  if (t < TA) sA[t][35] = 0;
  for (int i = t; i < TA * 28; i += 256) {
    int a = i / 28, c = 164 + i - a * 28;
    sA[a][c] = 0;
  }
  __syncthreads();

  const unsigned short* gsh = gm - (size_t)M_TREE * H;
  for (int la = wave * 8; la < TA; la += 32) {
    unsigned int u[8][MAXNB];
#pragma unroll
    for (int p = 0; p < 8; ++p) {
      const int* ig = &sAG[(la + p) * MAXNB];
#pragma unroll
      for (int j = 0; j < MAXNB; ++j) {
        int idx = __builtin_amdgcn_readfirstlane(ig[j]);
        const unsigned short* r = ((idx < M_TREE) ? tmsg : gsh) + (size_t)idx * H;
        u[p][j] = *(const unsigned int*)(r + 2 * lane);
      }
    }
#pragma unroll
    for (int p = 0; p < 8; ++p) {
      float a0 = 0.f, a1 = 0.f;
#pragma unroll
      for (int j = 0; j < MAXNB; ++j) bfdot_acc(u[p][j], a0, a1);
      unsigned int packed = ((unsigned int)f32_to_bf16(a1) << 16) | (unsigned int)f32_to_bf16(a0);
      *(unsigned int*)&sA[la + p][36 + 2 * lane] = packed;
    }
  }

  bf16x8 Bf[6][2];
#pragma unroll
  for (int kt = 0; kt < 6; ++kt)
#pragma unroll
    for (int nt = 0; nt < 2; ++nt)
      Bf[kt][nt] = *(const bf16x8*)(wob + ((wave * 2 + nt) * 16 + n16) * KPAD + kt * 32 + quad * 8);
  __syncthreads();

  f32x4 acc[4][2];
  f32x4 zero = {0.f, 0.f, 0.f, 0.f};
#pragma unroll
  for (int mt = 0; mt < 4; ++mt) { acc[mt][0] = zero; acc[mt][1] = zero; }
#pragma unroll
  for (int kt = 0; kt < 6; ++kt)
#pragma unroll
    for (int mt = 0; mt < 4; ++mt) {
      bf16x8 av = *(const bf16x8*)&sA[mt * 16 + n16][kt * 32 + quad * 8];
      acc[mt][0] = __builtin_amdgcn_mfma_f32_16x16x32_bf16(av, Bf[kt][0], acc[mt][0], 0, 0, 0);
      acc[mt][1] = __builtin_amdgcn_mfma_f32_16x16x32_bf16(av, Bf[kt][1], acc[mt][1], 0, 0, 0);
    }

  float bo[2] = { b_o[(wave * 2) * 16 + n16], b_o[(wave * 2 + 1) * 16 + n16] };
  float part[2][2] = {{0.f,0.f},{0.f,0.f}};
#pragma unroll
  for (int mt = 0; mt < 4; ++mt)
#pragma unroll
    for (int nt = 0; nt < 2; ++nt)
#pragma unroll
      for (int r = 0; r < 4; ++r)
        part[mt >> 1][nt] += fmaxf(acc[mt][nt][r] + bo[nt], 0.f);
#pragma unroll
  for (int mol = 0; mol < 2; ++mol)
#pragma unroll
    for (int nt = 0; nt < 2; ++nt) {
      float p = part[mol][nt];
      p += __shfl_xor(p, 16);
      p += __shfl_xor(p, 32);
      if (lane < 16)
        out[(blk * 2 + mol) * H + (wave * 2 + nt) * 16 + lane] = p * (1.0f / APM);
    }
}

extern "C" void kernel_launch(void* const* d_in, const int* in_sizes, int n_in,
                              void* d_out, int out_size, void* d_ws, size_t ws_size,
                              hipStream_t stream) {
  (void)in_sizes; (void)n_in; (void)out_size; (void)ws_size;
  const float* atom_feats   = (const float*)d_in[0];
  const float* bond_feats   = (const float*)d_in[1];
  const float* tree_message = (const float*)d_in[2];
  const int*   atom_graph   = (const int*)d_in[3];
  const int*   bond_graph   = (const int*)d_in[4];
  const float* W_i = (const float*)d_in[6];
  const float* W_h = (const float*)d_in[7];
  const float* W_o = (const float*)d_in[8];
  const float* b_o = (const float*)d_in[9];
  float* out = (float*)d_out;

  char* ws = (char*)d_ws;
  unsigned short* tmsg = (unsigned short*)(ws);                    //  8,388,608 B
  unsigned short* whb  = (unsigned short*)(ws + 8388608);
  unsigned short* wob  = (unsigned short*)(ws + 8421376);
  unsigned short* wib  = (unsigned short*)(ws + 8470528);
  unsigned short* h0   = (unsigned short*)(ws + 8486912);          // 67,108,864 B
  unsigned short* gm0  = (unsigned short*)(ws + 75595776);
  unsigned short* gm1  = (unsigned short*)(ws + 142704640);

  prep<<<4288, 256, 0, stream>>>(tree_message, W_h, W_o, W_i, tmsg, whb, wob, wib);
  wi_gemm<<<NBOND / 128, 256, 0, stream>>>(bond_feats, wib, h0);
  mp_step<<<NBOND / TB, 256, 0, stream>>>(h0,  gm0, h0, tmsg, bond_graph, whb);
  mp_step<<<NBOND / TB, 256, 0, stream>>>(gm0, gm1, h0, tmsg, bond_graph, whb);
  mp_step<<<NBOND / TB, 256, 0, stream>>>(gm1, gm0, h0, tmsg, bond_graph, whb);
  mp_step<<<NBOND / TB, 256, 0, stream>>>(gm0, gm1, h0, tmsg, bond_graph, whb);
  mp_step<<<NBOND / TB, 256, 0, stream>>>(gm1, gm0, h0, tmsg, bond_graph, whb);
  readout<<<NATOM / TA, 256, 0, stream>>>(atom_feats, gm0, tmsg, atom_graph, wob, b_o, out);
}

// Round 3
// 753.732 us; speedup vs baseline: 1.0782x; 1.0288x over previous
//
#include <hip/hip_runtime.h>

// ---- problem constants ----
#define H       128
#define MAXNB   10
#define M_TREE  32768
#define NBOND   262144
#define NATOM   131072
#define FATOM   35
#define FBOND   40
#define FOUT    163
#define KPAD    192
#define APM     32
#define TB      64      // bonds per block in mp_step
#define TA      64      // atoms per block in readout

typedef __bf16 bf16x8 __attribute__((ext_vector_type(8)));
typedef float  f32x4  __attribute__((ext_vector_type(4)));
typedef unsigned int u32x4 __attribute__((ext_vector_type(4)));
typedef unsigned int u32x2 __attribute__((ext_vector_type(2)));
typedef int          i32x4 __attribute__((ext_vector_type(4)));
typedef int          i32x2 __attribute__((ext_vector_type(2)));

__device__ __forceinline__ unsigned short f32_to_bf16(float f) {
  unsigned int u = __float_as_uint(f);
  u += 0x7FFFu + ((u >> 16) & 1u);   // RNE (no NaN in this data)
  return (unsigned short)(u >> 16);
}
// packed pair: relu(bf16(a) + bf16(h)) -> packed bf16
__device__ __forceinline__ unsigned int bfpair_addrelu(unsigned int a, unsigned int h) {
  float a0 = __uint_as_float(a << 16), a1 = __uint_as_float(a & 0xFFFF0000u);
  float h0v = __uint_as_float(h << 16), h1v = __uint_as_float(h & 0xFFFF0000u);
  float r0 = fmaxf(a0 + h0v, 0.f), r1 = fmaxf(a1 + h1v, 0.f);
  return ((unsigned int)f32_to_bf16(r1) << 16) | (unsigned int)f32_to_bf16(r0);
}
// a0 += lo(u), a1 += hi(u): 2 VALU ops instead of 4 (exact: bf16*1.0, f32 acc)
__device__ __forceinline__ void bfdot_acc(unsigned int u, float& a0, float& a1) {
  asm("v_dot2_f32_bf16 %0, %1, %2, %0" : "+v"(a0) : "v"(u), "v"(0x00003F80u));
  asm("v_dot2_f32_bf16 %0, %1, %2, %0" : "+v"(a1) : "v"(u), "v"(0x3F800000u));
}
__device__ __forceinline__ unsigned int pack2(float a0, float a1) {
  return ((unsigned int)f32_to_bf16(a1) << 16) | (unsigned int)f32_to_bf16(a0);
}

// ---- prep: tmsg -> heads of BOTH combined buffers; padded bf16 weights ----
__global__ __launch_bounds__(256) void prep(const float* __restrict__ tm,
                                            const float* __restrict__ wh,
                                            const float* __restrict__ wo,
                                            const float* __restrict__ wi,
                                            unsigned short* __restrict__ tA,
                                            unsigned short* __restrict__ tB,
                                            unsigned short* __restrict__ whb,
                                            unsigned short* __restrict__ wob,
                                            unsigned short* __restrict__ wib) {
  const int blk = blockIdx.x;
  if (blk < 4096) {
    int i = (blk * 256 + threadIdx.x) * 4;      // < 4,194,304
    f32x4 v = __builtin_nontemporal_load((const f32x4*)(tm + i));
    u32x2 p;
    p.x = (unsigned int)f32_to_bf16(v.x) | ((unsigned int)f32_to_bf16(v.y) << 16);
    p.y = (unsigned int)f32_to_bf16(v.z) | ((unsigned int)f32_to_bf16(v.w) << 16);
    *(u32x2*)(tA + i) = p;
    *(u32x2*)(tB + i) = p;
    return;
  }
  int j = (blk - 4096) * 256 + threadIdx.x;
  const int n2 = H * H;                 // 16,384
  const int n3 = H * KPAD;              // 24,576
  const int n4 = H * 64;                //  8,192
  if (j < n2) { whb[j] = f32_to_bf16(wh[j]); return; }
  int k = j - n2;
  if (k < n3) {
    // readout sA layout: feats 0..34, zeros 35..39, nei 40..167, zeros 168..191
    int g = k / KPAD, kk = k - g * KPAD;
    float v = 0.f;
    if (kk < 35)                   v = wo[g * FOUT + kk];
    else if (kk >= 40 && kk < 168) v = wo[g * FOUT + kk - 5];
    wob[k] = f32_to_bf16(v);
    return;
  }
  int m = k - n3;
  if (m < n4) {
    int g = m / 64, kk = m - g * 64;
    wib[m] = (kk < FBOND) ? f32_to_bf16(wi[g * FBOND + kk]) : (unsigned short)0;
  }
}

// ---- h0 = relu(bond_feats @ W_i^T): store bias copy AND buffer-A tail (gather src) ----
__global__ __launch_bounds__(256, 3) void wi_gemm(const float* __restrict__ bond_feats,
                                                  const unsigned short* __restrict__ wib,
                                                  unsigned short* __restrict__ h0,
                                                  unsigned short* __restrict__ h0A) {
  __shared__ unsigned short sF[128][72];
  const int t = threadIdx.x;
  const int lane = t & 63;
  const int wave = t >> 6;
  const int n16 = lane & 15;
  const int quad = lane >> 4;
  const int b0 = blockIdx.x * 128;

#pragma unroll
  for (int c = 0; c < 5; ++c) {
    int q = c * 256 + t;
    f32x4 v = __builtin_nontemporal_load((const f32x4*)(bond_feats + (size_t)b0 * FBOND + q * 4));
    int flat = q * 4;
    int row = flat / 40, col = flat - row * 40;
    u32x2 p;
    p.x = (unsigned int)f32_to_bf16(v.x) | ((unsigned int)f32_to_bf16(v.y) << 16);
    p.y = (unsigned int)f32_to_bf16(v.z) | ((unsigned int)f32_to_bf16(v.w) << 16);
    *(u32x2*)&sF[row][col] = p;
  }
  for (int i = t; i < 128 * 24; i += 256) {    // zero cols 40..63
    int b = i / 24, c = 40 + i - b * 24;
    sF[b][c] = 0;
  }
  bf16x8 Bf[2][2];
#pragma unroll
  for (int kt = 0; kt < 2; ++kt)
#pragma unroll
    for (int nt = 0; nt < 2; ++nt)
      Bf[kt][nt] = *(const bf16x8*)(wib + ((wave * 2 + nt) * 16 + n16) * 64 + kt * 32 + quad * 8);
  __syncthreads();

  f32x4 acc[8][2];
  f32x4 zero = {0.f, 0.f, 0.f, 0.f};
#pragma unroll
  for (int mt = 0; mt < 8; ++mt) { acc[mt][0] = zero; acc[mt][1] = zero; }
#pragma unroll
  for (int kt = 0; kt < 2; ++kt)
#pragma unroll
    for (int mt = 0; mt < 8; ++mt) {
      bf16x8 av = *(const bf16x8*)&sF[mt * 16 + n16][kt * 32 + quad * 8];
      acc[mt][0] = __builtin_amdgcn_mfma_f32_16x16x32_bf16(av, Bf[kt][0], acc[mt][0], 0, 0, 0);
      acc[mt][1] = __builtin_amdgcn_mfma_f32_16x16x32_bf16(av, Bf[kt][1], acc[mt][1], 0, 0, 0);
    }
#pragma unroll
  for (int mt = 0; mt < 8; ++mt)
#pragma unroll
    for (int nt = 0; nt < 2; ++nt) {
      const int col = (wave * 2 + nt) * 16 + n16;
#pragma unroll
      for (int r = 0; r < 4; ++r) {
        const int b = b0 + mt * 16 + quad * 4 + r;
        unsigned short hv = f32_to_bf16(fmaxf(acc[mt][nt][r], 0.f));
        h0 [(size_t)b * H + col] = hv;
        h0A[(size_t)b * H + col] = hv;
      }
    }
}

// ---- one MP round: gm_out = relu(h0 + gather(src)@W_h^T) ----
// src is combined [tmsg(32768 rows); gm(262144 rows)] -> raw graph indices address rows
// directly off one SGPR base with a 32-bit voffset (idx*256 + sublane*16).
// Gather: 4x16-lane groups, each group loads a FULL row via dwordx4 -> one instruction
// moves 4 rows (1 KB); u4[10] holds 40 rows (10 KB) in flight per wave at ~76 VGPRs.
__global__ __launch_bounds__(256, 6) void mp_step(const unsigned short* __restrict__ src,
                                                  unsigned short* __restrict__ gm_out,
                                                  const unsigned short* __restrict__ h0,
                                                  const int* __restrict__ bond_graph,
                                                  const unsigned short* __restrict__ whb) {
  __shared__ unsigned short snei[TB][136];   // 17408 B
  __shared__ int sBG[TB][16];                //  4096 B (padded rows: aligned b128 reads)
  const int t = threadIdx.x;
  const int lane = t & 63;
  const int wave = t >> 6;
  const int n16 = lane & 15;
  const int quad = lane >> 4;
  const int b0 = blockIdx.x * TB;

  for (int i = t; i < TB * MAXNB; i += 256) {
    int b = i / MAXNB, j = i - b * MAXNB;
    sBG[b][j] = bond_graph[(size_t)b0 * MAXNB + i];
  }
  __syncthreads();

  const unsigned char* sp = (const unsigned char*)src;
  const unsigned int so = (unsigned int)n16 * 16u;
  // each wave: 16 bonds, 4 bonds per iteration (one per 16-lane group)
  for (int it = 0; it < 4; ++it) {
    const int lb = wave * 16 + it * 4 + quad;
    i32x4 iv0 = *(const i32x4*)&sBG[lb][0];
    i32x4 iv1 = *(const i32x4*)&sBG[lb][4];
    i32x2 iv2 = *(const i32x2*)&sBG[lb][8];
    unsigned int ix[10] = {(unsigned int)iv0.x, (unsigned int)iv0.y, (unsigned int)iv0.z,
                           (unsigned int)iv0.w, (unsigned int)iv1.x, (unsigned int)iv1.y,
                           (unsigned int)iv1.z, (unsigned int)iv1.w, (unsigned int)iv2.x,
                           (unsigned int)iv2.y};
    u32x4 u4[10];
#pragma unroll
    for (int j = 0; j < MAXNB; ++j)
      u4[j] = *(const u32x4*)(sp + (ix[j] * 256u + so));
    float ac0 = 0.f, ac1 = 0.f, ac2 = 0.f, ac3 = 0.f;
    float ac4 = 0.f, ac5 = 0.f, ac6 = 0.f, ac7 = 0.f;
#pragma unroll
    for (int j = 0; j < MAXNB; ++j) {
      bfdot_acc(u4[j].x, ac0, ac1);
      bfdot_acc(u4[j].y, ac2, ac3);
      bfdot_acc(u4[j].z, ac4, ac5);
      bfdot_acc(u4[j].w, ac6, ac7);
    }
    u32x4 o;
    o.x = pack2(ac0, ac1);
    o.y = pack2(ac2, ac3);
    o.z = pack2(ac4, ac5);
    o.w = pack2(ac6, ac7);
    *(u32x4*)&snei[lb][n16 * 8] = o;   // byte off = 272*lb + 16*n16: 16B-aligned
  }

  // W_h^T fragments (after gather to limit register overlap): 32 VGPRs
  bf16x8 Bf[4][2];
#pragma unroll
  for (int kt = 0; kt < 4; ++kt)
#pragma unroll
    for (int nt = 0; nt < 2; ++nt)
      Bf[kt][nt] = *(const bf16x8*)(whb + ((wave * 2 + nt) * 16 + n16) * H + kt * 32 + quad * 8);
  __syncthreads();

  f32x4 acc[4][2];
  f32x4 zero = {0.f, 0.f, 0.f, 0.f};
#pragma unroll
  for (int mt = 0; mt < 4; ++mt) { acc[mt][0] = zero; acc[mt][1] = zero; }
#pragma unroll
  for (int kt = 0; kt < 4; ++kt)
#pragma unroll
    for (int mt = 0; mt < 4; ++mt) {
      bf16x8 av = *(const bf16x8*)&snei[mt * 16 + n16][kt * 32 + quad * 8];
      acc[mt][0] = __builtin_amdgcn_mfma_f32_16x16x32_bf16(av, Bf[kt][0], acc[mt][0], 0, 0, 0);
      acc[mt][1] = __builtin_amdgcn_mfma_f32_16x16x32_bf16(av, Bf[kt][1], acc[mt][1], 0, 0, 0);
    }
  __syncthreads();   // all MFMA reads of snei done

  // stage acc -> snei as bf16
#pragma unroll
  for (int mt = 0; mt < 4; ++mt)
#pragma unroll
    for (int nt = 0; nt < 2; ++nt) {
      const int col = (wave * 2 + nt) * 16 + n16;
#pragma unroll
      for (int r = 0; r < 4; ++r)
        snei[mt * 16 + quad * 4 + r][col] = f32_to_bf16(acc[mt][nt][r]);
    }
  __syncthreads();

  // vectorized epilogue: 64 rows x 16 chunks = 1024 -> 4/thread
  const size_t gbase = (size_t)b0 * H;
#pragma unroll
  for (int c = 0; c < 4; ++c) {
    int fl = c * 256 + t;
    int row = fl >> 4;
    int col = (fl & 15) * 8;
    u32x4 a4 = *(const u32x4*)&snei[row][col];
    u32x4 h4 = *(const u32x4*)(h0 + gbase + (size_t)row * H + col);
    u32x4 o4;
    o4.x = bfpair_addrelu(a4.x, h4.x);
    o4.y = bfpair_addrelu(a4.y, h4.y);
    o4.z = bfpair_addrelu(a4.z, h4.z);
    o4.w = bfpair_addrelu(a4.w, h4.w);
    *(u32x4*)(gm_out + gbase + (size_t)row * H + col) = o4;
  }
}

// ---- readout: 64 atoms (2 mols)/block, grouped gather from combined buffer ----
__global__ __launch_bounds__(256, 5) void readout(const float* __restrict__ atom_feats,
                                                  const unsigned short* __restrict__ src,
                                                  const int* __restrict__ atom_graph,
                                                  const unsigned short* __restrict__ wob,
                                                  const float* __restrict__ b_o,
                                                  float* __restrict__ out) {
  __shared__ unsigned short sA[TA][208];     // 26624 B (row 416 B: 16B-aligned cols)
  __shared__ int sAG[TA][16];                //  4096 B
  const int t = threadIdx.x;
  const int lane = t & 63;
  const int wave = t >> 6;
  const int n16 = lane & 15;
  const int quad = lane >> 4;
  const int blk = blockIdx.x;
  const int abase = blk * TA;

  for (int i = t; i < TA * MAXNB; i += 256) {
    int a = i / MAXNB, j = i - a * MAXNB;
    sAG[a][j] = __builtin_nontemporal_load(atom_graph + (size_t)abase * MAXNB + i);
  }
  for (int i = t; i < TA * FATOM; i += 256) {
    int a = i / FATOM, f = i - a * FATOM;
    sA[a][f] = f32_to_bf16(__builtin_nontemporal_load(atom_feats + (size_t)abase * FATOM + i));
  }
  if (t < TA) {
#pragma unroll
    for (int c = 35; c < 40; ++c) sA[t][c] = 0;
  }
  for (int i = t; i < TA * 24; i += 256) {   // zero cols 168..191 (MFMA K-range tail)
    int a = i / 24, c = 168 + i - a * 24;
    sA[a][c] = 0;
  }
  __syncthreads();

  const unsigned char* sp = (const unsigned char*)src;
  const unsigned int so = (unsigned int)n16 * 16u;
  for (int it = 0; it < 4; ++it) {
    const int la = wave * 16 + it * 4 + quad;
    i32x4 iv0 = *(const i32x4*)&sAG[la][0];
    i32x4 iv1 = *(const i32x4*)&sAG[la][4];
    i32x2 iv2 = *(const i32x2*)&sAG[la][8];
    unsigned int ix[10] = {(unsigned int)iv0.x, (unsigned int)iv0.y, (unsigned int)iv0.z,
                           (unsigned int)iv0.w, (unsigned int)iv1.x, (unsigned int)iv1.y,
                           (unsigned int)iv1.z, (unsigned int)iv1.w, (unsigned int)iv2.x,
                           (unsigned int)iv2.y};
    u32x4 u4[10];
#pragma unroll
    for (int j = 0; j < MAXNB; ++j)
      u4[j] = *(const u32x4*)(sp + (ix[j] * 256u + so));
    float ac0 = 0.f, ac1 = 0.f, ac2 = 0.f, ac3 = 0.f;
    float ac4 = 0.f, ac5 = 0.f, ac6 = 0.f, ac7 = 0.f;
#pragma unroll
    for (int j = 0; j < MAXNB; ++j) {
      bfdot_acc(u4[j].x, ac0, ac1);
      bfdot_acc(u4[j].y, ac2, ac3);
      bfdot_acc(u4[j].z, ac4, ac5);
      bfdot_acc(u4[j].w, ac6, ac7);
    }
    u32x4 o;
    o.x = pack2(ac0, ac1);
    o.y = pack2(ac2, ac3);
    o.z = pack2(ac4, ac5);
    o.w = pack2(ac6, ac7);
    *(u32x4*)&sA[la][40 + n16 * 8] = o;   // byte off = 416*la + 80 + 16*n16: 16B-aligned
  }

  bf16x8 Bf[6][2];
#pragma unroll
  for (int kt = 0; kt < 6; ++kt)
#pragma unroll
    for (int nt = 0; nt < 2; ++nt)
      Bf[kt][nt] = *(const bf16x8*)(wob + ((wave * 2 + nt) * 16 + n16) * KPAD + kt * 32 + quad * 8);
  __syncthreads();

  f32x4 acc[4][2];
  f32x4 zero = {0.f, 0.f, 0.f, 0.f};
#pragma unroll
  for (int mt = 0; mt < 4; ++mt) { acc[mt][0] = zero; acc[mt][1] = zero; }
#pragma unroll
  for (int kt = 0; kt < 6; ++kt)
#pragma unroll
    for (int mt = 0; mt < 4; ++mt) {
      bf16x8 av = *(const bf16x8*)&sA[mt * 16 + n16][kt * 32 + quad * 8];
      acc[mt][0] = __builtin_amdgcn_mfma_f32_16x16x32_bf16(av, Bf[kt][0], acc[mt][0], 0, 0, 0);
      acc[mt][1] = __builtin_amdgcn_mfma_f32_16x16x32_bf16(av, Bf[kt][1], acc[mt][1], 0, 0, 0);
    }

  float bo[2] = { b_o[(wave * 2) * 16 + n16], b_o[(wave * 2 + 1) * 16 + n16] };
  float part[2][2] = {{0.f,0.f},{0.f,0.f}};
#pragma unroll
  for (int mt = 0; mt < 4; ++mt)
#pragma unroll
    for (int nt = 0; nt < 2; ++nt)
#pragma unroll
      for (int r = 0; r < 4; ++r)
        part[mt >> 1][nt] += fmaxf(acc[mt][nt][r] + bo[nt], 0.f);
#pragma unroll
  for (int mol = 0; mol < 2; ++mol)
#pragma unroll
    for (int nt = 0; nt < 2; ++nt) {
      float p = part[mol][nt];
      p += __shfl_xor(p, 16);
      p += __shfl_xor(p, 32);
      if (lane < 16)
        out[(blk * 2 + mol) * H + (wave * 2 + nt) * 16 + lane] = p * (1.0f / APM);
    }
}

extern "C" void kernel_launch(void* const* d_in, const int* in_sizes, int n_in,
                              void* d_out, int out_size, void* d_ws, size_t ws_size,
                              hipStream_t stream) {
  (void)in_sizes; (void)n_in; (void)out_size; (void)ws_size;
  const float* atom_feats   = (const float*)d_in[0];
  const float* bond_feats   = (const float*)d_in[1];
  const float* tree_message = (const float*)d_in[2];
  const int*   atom_graph   = (const int*)d_in[3];
  const int*   bond_graph   = (const int*)d_in[4];
  const float* W_i = (const float*)d_in[6];
  const float* W_h = (const float*)d_in[7];
  const float* W_o = (const float*)d_in[8];
  const float* b_o = (const float*)d_in[9];
  float* out = (float*)d_out;

  char* ws = (char*)d_ws;
  // combined buffers: [tmsg 32768 rows ; gm 262144 rows] x 256 B rows = 75,497,472 B
  unsigned short* A    = (unsigned short*)(ws);
  unsigned short* B    = (unsigned short*)(ws + 75497472);
  unsigned short* h0   = (unsigned short*)(ws + 150994944);        // 67,108,864 B (bias copy)
  unsigned short* whb  = (unsigned short*)(ws + 218103808);
  unsigned short* wob  = (unsigned short*)(ws + 218136576);
  unsigned short* wib  = (unsigned short*)(ws + 218185728);        // end: 218,202,112 B
  unsigned short* Atail = A + (size_t)M_TREE * H;
  unsigned short* Btail = B + (size_t)M_TREE * H;

  prep<<<4288, 256, 0, stream>>>(tree_message, W_h, W_o, W_i, A, B, whb, wob, wib);
  wi_gemm<<<NBOND / 128, 256, 0, stream>>>(bond_feats, wib, h0, Atail);
  mp_step<<<NBOND / TB, 256, 0, stream>>>(A, Btail, h0, bond_graph, whb);
  mp_step<<<NBOND / TB, 256, 0, stream>>>(B, Atail, h0, bond_graph, whb);
  mp_step<<<NBOND / TB, 256, 0, stream>>>(A, Btail, h0, bond_graph, whb);
  mp_step<<<NBOND / TB, 256, 0, stream>>>(B, Atail, h0, bond_graph, whb);
  mp_step<<<NBOND / TB, 256, 0, stream>>>(A, Btail, h0, bond_graph, whb);
  readout<<<NATOM / TA, 256, 0, stream>>>(atom_feats, B, atom_graph, wob, b_o, out);
}